// Round 5
// baseline (34.217 us; speedup 1.0000x reference)
//
#include <hip/hip_runtime.h>

#define DEVFN __device__ __forceinline__

typedef float f32x4 __attribute__((ext_vector_type(4)));

DEVFN float min3f(float a, float b, float c) { return fminf(fminf(a, b), c); }
DEVFN float max3f(float a, float b, float c) { return fmaxf(fmaxf(a, b), c); }
DEVFN float med3f(float a, float b, float c) {
    return fmaxf(fminf(a, b), fminf(fmaxf(a, b), c));
}

// Fixed shape: 16 x 3 x 512 x 512 f32, 3x3 median with zero padding,
// plus pass-through copy of `cover` into out+n.
// Each thread: 4-row x 4-col output tile (6 input rows in registers).
// XCD-aware chunked blockIdx swizzle keeps halo rows in the same XCD's L2.
// Stores are REGULAR (cached) this round: working set (in 96 MiB + out
// 96 MiB = 192 MiB) fits the 256 MiB L3, so letting output lines dwell
// dirty in L3 may collapse steady-state HBM write traffic across replays
// (round-4's nontemporal hint forced the full 98 MB to HBM every replay).
__global__ __launch_bounds__(256) void median3x3_r4_swz_c(
        const float* __restrict__ in, const float* __restrict__ cover,
        float* __restrict__ out, float* __restrict__ out2, int chunk) {
    constexpr int W = 512;
    constexpr int H = 512;

    // bijective chunked XCD swizzle (grid % 8 == 0)
    int bid = blockIdx.x;
    int swz = (bid & 7) * chunk + (bid >> 3);
    int tid = swz * blockDim.x + threadIdx.x;

    int rg  = tid >> 7;                 // row-band id, 4 rows each
    int g   = tid & 127;                // horizontal group
    int x0  = g << 2;
    int plane = rg >> 7;                // 128 row-bands per 512-row plane
    int y0  = (rg & 127) << 2;          // first output row in plane

    int rbase = (plane << 18) + (y0 << 9) + x0;   // element index of (y0, x0)
    const float* rowp = in + rbase;

    // v[0] = row y0-1 (halo), v[1..4] = rows y0..y0+3, v[5] = row y0+4 (halo)
    float v[6][6];

    #pragma unroll
    for (int t = 0; t < 4; ++t) {
        const float* rp = rowp + (t << 9);
        f32x4 c = *reinterpret_cast<const f32x4*>(rp);
        v[t + 1][1] = c.x; v[t + 1][2] = c.y; v[t + 1][3] = c.z; v[t + 1][4] = c.w;
        v[t + 1][0] = (x0 > 0)     ? rp[-1] : 0.0f;
        v[t + 1][5] = (x0 + 4 < W) ? rp[4]  : 0.0f;
    }
    if (y0 > 0) {
        const float* rp = rowp - W;
        f32x4 c = *reinterpret_cast<const f32x4*>(rp);
        v[0][1] = c.x; v[0][2] = c.y; v[0][3] = c.z; v[0][4] = c.w;
        v[0][0] = (x0 > 0)     ? rp[-1] : 0.0f;
        v[0][5] = (x0 + 4 < W) ? rp[4]  : 0.0f;
    } else {
        #pragma unroll
        for (int j = 0; j < 6; ++j) v[0][j] = 0.0f;
    }
    if (y0 + 4 < H) {
        const float* rp = rowp + (4 << 9);
        f32x4 c = *reinterpret_cast<const f32x4*>(rp);
        v[5][1] = c.x; v[5][2] = c.y; v[5][3] = c.z; v[5][4] = c.w;
        v[5][0] = (x0 > 0)     ? rp[-1] : 0.0f;
        v[5][5] = (x0 + 4 < W) ? rp[4]  : 0.0f;
    } else {
        #pragma unroll
        for (int j = 0; j < 6; ++j) v[5][j] = 0.0f;
    }

    // cover pass-through (independent loads, overlap with median compute)
    f32x4 cv[4];
    #pragma unroll
    for (int t = 0; t < 4; ++t)
        cv[t] = *reinterpret_cast<const f32x4*>(cover + rbase + (t << 9));

    #pragma unroll
    for (int t = 0; t < 4; ++t) {
        float cmn[6], cmd[6], cmx[6];
        #pragma unroll
        for (int j = 0; j < 6; ++j) {
            float a = v[t][j], b = v[t + 1][j], c = v[t + 2][j];
            cmn[j] = min3f(a, b, c);
            cmx[j] = max3f(a, b, c);
            cmd[j] = med3f(a, b, c);
        }
        f32x4 o;
        #pragma unroll
        for (int i = 0; i < 4; ++i) {
            float lo = max3f(cmn[i], cmn[i + 1], cmn[i + 2]);
            float hi = min3f(cmx[i], cmx[i + 1], cmx[i + 2]);
            float mi = med3f(cmd[i], cmd[i + 1], cmd[i + 2]);
            o[i] = med3f(lo, mi, hi);
        }
        *reinterpret_cast<f32x4*>(out  + rbase + (t << 9)) = o;
        *reinterpret_cast<f32x4*>(out2 + rbase + (t << 9)) = cv[t];
    }
}

extern "C" void kernel_launch(void* const* d_in, const int* in_sizes, int n_in,
                              void* d_out, int out_size, void* d_ws, size_t ws_size,
                              hipStream_t stream) {
    const float* noised = (const float*)d_in[0];
    const float* cover  = (const float*)d_in[1];
    float* out = (float*)d_out;

    const int n = in_sizes[0];                  // 16*3*512*512 = 12582912
    const int rows_total = n / 512;             // 24576
    const int row_groups = rows_total / 4;      // 6144
    const int threads_total = row_groups * 128; // 786432
    const int block = 256;
    const int grid = threads_total / block;     // 3072 (divisible by 8)
    const int chunk = grid / 8;                 // 384

    median3x3_r4_swz_c<<<grid, block, 0, stream>>>(noised, cover, out, out + n, chunk);
}